// Round 1
// baseline (920.457 us; speedup 1.0000x reference)
//
#include <hip/hip_runtime.h>
#include <hip/hip_bf16.h>
#include <math.h>

#define N_NODES 10000
#define K1 10
#define K2 25
#define DIM 64
#define OUT 128
#define NGRAPH 64

// ---------------------------------------------------------------------------
// Kernel A: per node i (one block):
//   for j in 0..9:  r = i*10+j
//     mean_j = mean over 25 rows of h2[r*25 .. r*25+24]            (64)
//     x_j    = concat(h1[r], mean_j)                               (128)
//     y_j    = relu(x_j @ w0 + b0)                                 (128)
//   a12mean[i] = (1/10) * sum_j y_j                                (128)
// w0 held in registers: thread t owns col c=t&127, k-half h=t>>7 (64 regs).
// ---------------------------------------------------------------------------
__global__ __launch_bounds__(256, 4) void kA(const float* __restrict__ h1,
                                             const float* __restrict__ h2,
                                             const float* __restrict__ w0,
                                             const float* __restrict__ b0,
                                             float* __restrict__ a12mean)
{
    __shared__ float  xbuf[K1][2 * DIM];   // 10 x 128 = 5 KB
    __shared__ float4 red4[16][16];        // 4 KB reduce scratch
    __shared__ float  pbuf[K1][OUT];       // 5 KB partial dot products

    const int t    = threadIdx.x;
    const int node = blockIdx.x;
    const int c    = t & 127;
    const int h    = t >> 7;       // 0 or 1: which k-half of the dot product

    // --- w0 register slice: rows h*64+k, col c (coalesced per row) ---
    float w0r[64];
#pragma unroll
    for (int k = 0; k < 64; ++k)
        w0r[k] = w0[(h * 64 + k) * OUT + c];
    const float b0r = b0[c];

    // --- h1 rows for this node: 640 contiguous floats -> xbuf[j][0:64] ---
    {
        const float* h1b = h1 + (size_t)node * (K1 * DIM);
        for (int idx = t; idx < K1 * DIM; idx += 256)
            xbuf[idx >> 6][idx & 63] = h1b[idx];
    }

    // --- phase 1: mean over K2=25 h2 rows per child row j ---
    const int cc = t & 15;   // float4 column chunk (16 chunks of 4 = 64 cols)
    const int sl = t >> 4;   // row slice 0..15
    const float4* h2b = (const float4*)h2 + (size_t)node * (K1 * K2 * DIM / 4);
    for (int j = 0; j < K1; ++j) {
        const float4* bj = h2b + j * (K2 * DIM / 4);  // 400 contiguous float4
        float4 s = bj[sl * 16 + cc];                  // rows 0..15
        if (sl < 9) {                                 // rows 16..24
            float4 s2 = bj[(sl + 16) * 16 + cc];
            s.x += s2.x; s.y += s2.y; s.z += s2.z; s.w += s2.w;
        }
        red4[sl][cc] = s;
        __syncthreads();
        if (t < 64) {
            const float* rf = (const float*)red4;
            float sum = 0.f;
#pragma unroll
            for (int ss = 0; ss < 16; ++ss) sum += rf[ss * 64 + t];
            xbuf[j][DIM + t] = sum * (1.0f / K2);
        }
        __syncthreads();
    }

    // --- phase 2: 10 matvecs, accumulate relu outputs ---
    float myp[K1];
#pragma unroll
    for (int j = 0; j < K1; ++j) {
        const float4* xj = (const float4*)(&xbuf[j][h * DIM]);
        float p = 0.f;
#pragma unroll
        for (int k4 = 0; k4 < 16; ++k4) {
            float4 xv = xj[k4];
            p += xv.x * w0r[4 * k4 + 0];
            p += xv.y * w0r[4 * k4 + 1];
            p += xv.z * w0r[4 * k4 + 2];
            p += xv.w * w0r[4 * k4 + 3];
        }
        if (h == 1) pbuf[j][c] = p;
        else        myp[j]     = p;
    }
    __syncthreads();
    if (h == 0) {
        float acc = 0.f;
#pragma unroll
        for (int j = 0; j < K1; ++j) {
            float y = myp[j] + pbuf[j][c] + b0r;
            acc += (y > 0.f ? y : 0.f);
        }
        a12mean[(size_t)node * OUT + c] = acc * (1.0f / K1);
    }
}

// ---------------------------------------------------------------------------
// Kernel B: 16 nodes per block.
//   a01  = relu(concat(h0, mean_10(h1)) @ w0 + b0)
//   out  = relu(concat(a01, a12mean) @ w1 + b1)
//   seg[gid] += out  (gids sorted -> run-length local sum, flush via atomic)
// ---------------------------------------------------------------------------
__global__ __launch_bounds__(256, 2) void kB(const float* __restrict__ h0,
                                             const float* __restrict__ h1,
                                             const float* __restrict__ w0,
                                             const float* __restrict__ b0,
                                             const float* __restrict__ w1,
                                             const float* __restrict__ b1,
                                             const float* __restrict__ a12mean,
                                             const int*   __restrict__ gids,
                                             float* __restrict__ seg)
{
    __shared__ float x0[16][2 * DIM];    // 8 KB
    __shared__ float x1[16][2 * OUT];    // 16 KB
    __shared__ float pbuf[16][OUT];      // 8 KB

    const int t  = threadIdx.x;
    const int n0 = blockIdx.x * 16;
    const int c  = t & 127;
    const int hh = t >> 7;

    // w0 register slice (same layout as kA)
    float w0r[64];
#pragma unroll
    for (int k = 0; k < 64; ++k)
        w0r[k] = w0[(hh * 64 + k) * OUT + c];
    const float b0r = b0[c];

    // h0 rows -> x0[:, 0:64]
    for (int idx = t; idx < 16 * DIM; idx += 256)
        x0[idx >> 6][idx & 63] = h0[(size_t)n0 * DIM + idx];

    // mean over 10 h1 rows per node -> x0[:, 64:128]
    {
        const int col = t & 63, isub = t >> 6;
        for (int chunk = 0; chunk < 4; ++chunk) {
            const int il = chunk * 4 + isub;
            const float* b = h1 + (size_t)(n0 + il) * (K1 * DIM);
            float s = 0.f;
#pragma unroll
            for (int r = 0; r < K1; ++r) s += b[r * DIM + col];
            x0[il][DIM + col] = s * (1.0f / K1);
        }
    }

    // a12mean rows -> x1[:, 128:256]
    for (int idx = t; idx < 16 * OUT; idx += 256)
        x1[idx >> 7][OUT + (idx & 127)] = a12mean[(size_t)n0 * OUT + idx];
    __syncthreads();

    // a01 matvecs
    float myp[16];
#pragma unroll
    for (int i = 0; i < 16; ++i) {
        const float4* xi = (const float4*)(&x0[i][hh * DIM]);
        float p = 0.f;
#pragma unroll
        for (int k4 = 0; k4 < 16; ++k4) {
            float4 xv = xi[k4];
            p += xv.x * w0r[4 * k4 + 0] + xv.y * w0r[4 * k4 + 1]
               + xv.z * w0r[4 * k4 + 2] + xv.w * w0r[4 * k4 + 3];
        }
        if (hh == 1) pbuf[i][c] = p; else myp[i] = p;
    }
    __syncthreads();
    if (hh == 0) {
#pragma unroll
        for (int i = 0; i < 16; ++i) {
            float y = myp[i] + pbuf[i][c] + b0r;
            x1[i][c] = (y > 0.f ? y : 0.f);
        }
    }

    // w1 register slice: rows hh*128+k, col c  (w0r dead -> regs reusable)
    float w1r[128];
#pragma unroll
    for (int k = 0; k < 128; ++k)
        w1r[k] = w1[(hh * 128 + k) * OUT + c];
    const float b1r = b1[c];
    __syncthreads();   // covers x1 writes and pbuf reuse

    // round-1 matvecs
#pragma unroll
    for (int i = 0; i < 16; ++i) {
        const float4* xi = (const float4*)(&x1[i][hh * OUT]);
        float p = 0.f;
#pragma unroll
        for (int k4 = 0; k4 < 32; ++k4) {
            float4 xv = xi[k4];
            p += xv.x * w1r[4 * k4 + 0] + xv.y * w1r[4 * k4 + 1]
               + xv.z * w1r[4 * k4 + 2] + xv.w * w1r[4 * k4 + 3];
        }
        if (hh == 1) pbuf[i][c] = p; else myp[i] = p;
    }
    __syncthreads();
    if (hh == 0) {
        int   runGid = gids[n0];
        float runSum = 0.f;
#pragma unroll
        for (int i = 0; i < 16; ++i) {
            float y = myp[i] + pbuf[i][c] + b1r;
            y = (y > 0.f ? y : 0.f);
            const int g = gids[n0 + i];      // uniform across threads -> no divergence
            if (g != runGid) {
                atomicAdd(&seg[runGid * OUT + c], runSum);
                runSum = 0.f; runGid = g;
            }
            runSum += y;
        }
        atomicAdd(&seg[runGid * OUT + c], runSum);
    }
}

// ---------------------------------------------------------------------------
// Kernel C: readout MLP on seg (64 x 128) -> out (64 x 1). One wave per graph.
// ---------------------------------------------------------------------------
__global__ void kC(const float* __restrict__ seg,
                   const float* __restrict__ wr1, const float* __restrict__ br1,
                   const float* __restrict__ wr2, const float* __restrict__ br2,
                   const float* __restrict__ wr3, const float* __restrict__ br3,
                   float* __restrict__ out)
{
    __shared__ float r1[35], r2[35];
    const int g = blockIdx.x, l = threadIdx.x;
    const float* s = seg + (size_t)g * OUT;
    const float SCALE = 1.0507009873554805f;
    const float ALPHA = 1.6732632423543772f;

    if (l < 35) {
        float d = br1[l];
        for (int k = 0; k < OUT; ++k) d += s[k] * wr1[k * 35 + l];
        r1[l] = d > 0.f ? SCALE * d : SCALE * ALPHA * (expf(d) - 1.f);
    }
    __syncthreads();
    if (l < 35) {
        float d = br2[l];
        for (int k = 0; k < 35; ++k) d += r1[k] * wr2[k * 35 + l];
        r2[l] = d > 0.f ? SCALE * d : SCALE * ALPHA * (expf(d) - 1.f);
    }
    __syncthreads();
    if (l == 0) {
        float d = br3[0];
        for (int k = 0; k < 35; ++k) d += r2[k] * wr3[k];
        out[g] = d;
    }
}

extern "C" void kernel_launch(void* const* d_in, const int* in_sizes, int n_in,
                              void* d_out, int out_size, void* d_ws, size_t ws_size,
                              hipStream_t stream)
{
    const float* h0  = (const float*)d_in[0];
    const float* h1  = (const float*)d_in[1];
    const float* h2  = (const float*)d_in[2];
    const float* w0  = (const float*)d_in[3];
    const float* b0  = (const float*)d_in[4];
    const float* w1  = (const float*)d_in[5];
    const float* b1  = (const float*)d_in[6];
    const float* wr1 = (const float*)d_in[7];
    const float* br1 = (const float*)d_in[8];
    const float* wr2 = (const float*)d_in[9];
    const float* br2 = (const float*)d_in[10];
    const float* wr3 = (const float*)d_in[11];
    const float* br3 = (const float*)d_in[12];
    const int*  gids = (const int*)d_in[13];
    // d_in[14] = num_graphs (compile-time constant 64)

    float* a12mean = (float*)d_ws;                    // N*128 floats = 5.12 MB
    float* seg     = a12mean + (size_t)N_NODES * OUT; // 64*128 floats
    float* out     = (float*)d_out;

    hipMemsetAsync(seg, 0, NGRAPH * OUT * sizeof(float), stream);
    kA<<<N_NODES, 256, 0, stream>>>(h1, h2, w0, b0, a12mean);
    kB<<<N_NODES / 16, 256, 0, stream>>>(h0, h1, w0, b0, w1, b1, a12mean, gids, seg);
    kC<<<NGRAPH, 64, 0, stream>>>(seg, wr1, br1, wr2, br2, wr3, br3, out);
}